// Round 1
// 707.865 us; speedup vs baseline: 1.5562x; 1.5562x over previous
//
#include <hip/hip_runtime.h>

// WaveRNN cell, MI355X. B=32768 H=896 S=448 Q=256.
// Inputs/outputs are FLOAT32 (per reference dtypes). Internally: convert to
// bf16, run m97-style 128x128 MFMA tiles with global_load_lds width-16
// staging, f32 epilogues.
// R2 changes vs R1:
//  - gate_kernel: 3 gate passes (u,r,e) FUSED into one K-loop. A staged once
//    per K-step, 3 B tiles staged, acc[3][4][4]. 28 K-steps instead of 84;
//    A-traffic /3; no u/r bf16 packing round-trip.
//  - XCD-sibling swizzle on gate/stage1/stage2: 1-D grid, j-siblings of the
//    same A-tile placed consecutively on the same XCD (xcd = f&7) so A
//    re-reads hit that XCD's L2. (FETCH_SIZE showed 21x A refetch = 1.23 GB.)

typedef unsigned short u16;
typedef unsigned int u32;
typedef __attribute__((ext_vector_type(8))) short bf16x8;
typedef __attribute__((ext_vector_type(4))) float f32x4;

#define GAS __attribute__((address_space(1)))
#define LAS __attribute__((address_space(3)))

__device__ __forceinline__ u16 f2b(float f) {
  union { float f; u32 i; } v; v.f = f;
  return (u16)((v.i + 0x7fffu + ((v.i >> 16) & 1u)) >> 16);
}

__device__ __forceinline__ void gl_lds(const u16* g, u16* l) {
  __builtin_amdgcn_global_load_lds((const GAS void*)g, (LAS void*)l, 16, 0, 0);
}

// ---------------- f32 -> bf16 convert (prev_hidden) ----------------
__global__ void cvt_f32_bf16(const float* __restrict__ in, u16* __restrict__ outp) {
  const size_t i = ((size_t)blockIdx.x * 256 + threadIdx.x) * 4;
  const float4 v = *(const float4*)&in[i];
  ushort4 o;
  o.x = f2b(v.x); o.y = f2b(v.y); o.z = f2b(v.z); o.w = f2b(v.w);
  *(ushort4*)&outp[i] = o;
}

// --------- weight transpose, f32 row-major R x C -> bf16 C x R ---------
__global__ void transpose_f32_bf16(const float* __restrict__ in, u16* __restrict__ outp,
                                   int R, int C) {
  __shared__ u16 t[32][33];
  const int c0 = blockIdx.x * 32, r0 = blockIdx.y * 32;
  const int x = threadIdx.x, y = threadIdx.y;
  #pragma unroll
  for (int i = 0; i < 32; i += 8)
    t[y + i][x] = f2b(in[(size_t)(r0 + y + i) * C + (c0 + x)]);
  __syncthreads();
  #pragma unroll
  for (int i = 0; i < 32; i += 8)
    outp[(size_t)(c0 + y + i) * R + (r0 + x)] = t[x][y + i];
}

// ------------- 128x128 tile K-loop: A row-major, BT n-major (both k-contig) --
// 4 waves as 2x2 grid of 64x64; BK=32; acc[4][4] f32x4. (stage1/stage2)
__device__ __forceinline__ void gemm_tile_k(const u16* __restrict__ A, int lda,
                                            const u16* __restrict__ BT, int ldb,
                                            int K, u16* Al, u16* Bl,
                                            int wave, int lane, f32x4 (&acc)[4][4]) {
  const int wm = wave & 1, wn = wave >> 1;
  const int q = lane >> 4, l16 = lane & 15;
  const int sr = lane >> 2;          // staging sub-row 0..15
  const int sc = (lane & 3) * 8;     // staging col offset (elements)
  for (int k0 = 0; k0 < K; k0 += 32) {
    #pragma unroll
    for (int i = 0; i < 2; ++i) {
      const int rr = wave * 32 + i * 16;  // wave-uniform row base
      gl_lds(A + (size_t)(rr + sr) * lda + (k0 + sc), &Al[rr * 32]);
      gl_lds(BT + (size_t)(rr + sr) * ldb + (k0 + sc), &Bl[rr * 32]);
    }
    __syncthreads();
    bf16x8 af[4], bfr[4];
    #pragma unroll
    for (int t = 0; t < 4; ++t) {
      af[t]  = *(const bf16x8*)&Al[(wm * 64 + t * 16 + l16) * 32 + q * 8];
      bfr[t] = *(const bf16x8*)&Bl[(wn * 64 + t * 16 + l16) * 32 + q * 8];
    }
    #pragma unroll
    for (int mt = 0; mt < 4; ++mt)
      #pragma unroll
      for (int nt = 0; nt < 4; ++nt)
        acc[mt][nt] = __builtin_amdgcn_mfma_f32_16x16x32_bf16(af[mt], bfr[nt],
                                                              acc[mt][nt], 0, 0, 0);
    __syncthreads();
  }
}

__device__ __forceinline__ void zero_acc(f32x4 (&acc)[4][4]) {
  const f32x4 z = {0.f, 0.f, 0.f, 0.f};
  #pragma unroll
  for (int mt = 0; mt < 4; ++mt)
    #pragma unroll
    for (int nt = 0; nt < 4; ++nt)
      acc[mt][nt] = z;
}

// ---------------- fused gate kernel (single K-loop, 3 acc sets) --------------
// grid 1792 = 8 xcd * 32 m_local * 7 j. Swizzle: xcd = f&7 so the 7 j-siblings
// of each m0 run back-to-back on one XCD (A-tile L2 reuse).
__global__ __launch_bounds__(256, 2)
void gate_kernel(const u16* __restrict__ phb, const u16* __restrict__ wrt,
                 const float* __restrict__ phf,
                 const float* __restrict__ y2, const float* __restrict__ cc,
                 const float* __restrict__ wic, const float* __restrict__ wif,
                 const float* __restrict__ bu, const float* __restrict__ br,
                 const float* __restrict__ be,
                 float* __restrict__ houtf, u16* __restrict__ hb) {
  __shared__ u16 Al[128 * 32];
  __shared__ u16 Bl[3][128 * 32];
  __shared__ float rowy[3 * 128];
  const int tid = threadIdx.x;
  const int lane = tid & 63, wave = tid >> 6;
  const int f = blockIdx.x;
  const int xcd = f & 7, l = f >> 3;          // 224 blocks per XCD
  const int m0 = (xcd * 32 + l / 7) * 128;
  const int j0 = (l % 7) * 128;
  if (tid < 128) {
    const int r = m0 + tid;
    rowy[tid]       = y2[2 * r];
    rowy[128 + tid] = y2[2 * r + 1];
    rowy[256 + tid] = cc[r];
  }
  const int wm = wave & 1, wn = wave >> 1;
  const int q = lane >> 4, l16 = lane & 15;
  const int sr = lane >> 2, sc = (lane & 3) * 8;

  f32x4 acc[3][4][4];
  {
    const f32x4 z = {0.f, 0.f, 0.f, 0.f};
    #pragma unroll
    for (int s = 0; s < 3; ++s)
      #pragma unroll
      for (int mt = 0; mt < 4; ++mt)
        #pragma unroll
        for (int nt = 0; nt < 4; ++nt)
          acc[s][mt][nt] = z;
  }

  const u16* Ab  = phb + (size_t)m0 * 896;
  const u16* Bb0 = wrt + (size_t)(0 * 896 + j0) * 896;
  const u16* Bb1 = wrt + (size_t)(1 * 896 + j0) * 896;
  const u16* Bb2 = wrt + (size_t)(2 * 896 + j0) * 896;

  for (int k0 = 0; k0 < 896; k0 += 32) {
    #pragma unroll
    for (int i = 0; i < 2; ++i) {
      const int rr = wave * 32 + i * 16;      // wave-uniform row base
      const size_t go = (size_t)(rr + sr) * 896 + (k0 + sc);
      gl_lds(Ab  + go, &Al[rr * 32]);
      gl_lds(Bb0 + go, &Bl[0][rr * 32]);
      gl_lds(Bb1 + go, &Bl[1][rr * 32]);
      gl_lds(Bb2 + go, &Bl[2][rr * 32]);
    }
    __syncthreads();
    bf16x8 af[4];
    #pragma unroll
    for (int t = 0; t < 4; ++t)
      af[t] = *(const bf16x8*)&Al[(wm * 64 + t * 16 + l16) * 32 + q * 8];
    #pragma unroll
    for (int s = 0; s < 3; ++s) {
      bf16x8 bfr[4];
      #pragma unroll
      for (int t = 0; t < 4; ++t)
        bfr[t] = *(const bf16x8*)&Bl[s][(wn * 64 + t * 16 + l16) * 32 + q * 8];
      #pragma unroll
      for (int mt = 0; mt < 4; ++mt)
        #pragma unroll
        for (int nt = 0; nt < 4; ++nt)
          acc[s][mt][nt] = __builtin_amdgcn_mfma_f32_16x16x32_bf16(af[mt], bfr[nt],
                                                                   acc[s][mt][nt], 0, 0, 0);
    }
    __syncthreads();
  }

  // ---- fused epilogue: u, r, e, h in one place (no bf16 round-trip on u/r)
  const int jb = j0 + wn * 64;
  const int rb = wm * 64 + q * 4;
  #pragma unroll
  for (int nt = 0; nt < 4; ++nt) {
    const int j = jb + nt * 16 + l16;
    float wu0, wu1, wu2, wr0, wr1, wr2, we0, we1, we2;
    if (j < 448) {
      wu0 = wic[j];       wu1 = wic[1344 + j];       wu2 = 0.f;
      wr0 = wic[448 + j]; wr1 = wic[1792 + j];       wr2 = 0.f;
      we0 = wic[896 + j]; we1 = wic[2240 + j];       we2 = 0.f;
    } else {
      const int jf = j - 448;
      wu0 = wif[jf];       wu1 = wif[1344 + jf]; wu2 = wif[2688 + jf];
      wr0 = wif[448 + jf]; wr1 = wif[1792 + jf]; wr2 = wif[3136 + jf];
      we0 = wif[896 + jf]; we1 = wif[2240 + jf]; we2 = wif[3584 + jf];
    }
    const float bju = bu[j], bjr = br[j], bje = be[j];
    #pragma unroll
    for (int mt = 0; mt < 4; ++mt) {
      const int rl = rb + mt * 16;
      #pragma unroll
      for (int i = 0; i < 4; ++i) {
        const float y0 = rowy[rl + i], y1 = rowy[128 + rl + i], yc = rowy[256 + rl + i];
        const float gu = acc[0][mt][nt][i] + y0 * wu0 + y1 * wu1 + yc * wu2 + bju;
        const float gr = acc[1][mt][nt][i] + y0 * wr0 + y1 * wr1 + yc * wr2 + bjr;
        const float uu = 1.f / (1.f + __expf(-gu));
        const float rg = 1.f / (1.f + __expf(-gr));
        const float ev = tanhf(rg * acc[2][mt][nt][i] +
                               y0 * we0 + y1 * we1 + yc * we2 + bje);
        const size_t grow = (size_t)(m0 + rl + i);
        const float phv = phf[grow * 896 + j];
        const float h = uu * phv + (1.f - uu) * ev;
        houtf[grow * 896 + j] = h;
        hb[grow * 896 + j] = f2b(h);
      }
    }
  }
}

// ---------------- stage 1: T_z = relu(h_z @ W_O{1,3} + b), bf16 out ----------
// grid 2048 = 8 xcd * 64 mz_local * 4 j (swizzled; last j tile: rows >=448 of
// BT read garbage in-ws bytes; write masked by j<448).
__global__ __launch_bounds__(256, 2)
void stage1_kernel(const u16* __restrict__ hb, const u16* __restrict__ w1t,
                   const u16* __restrict__ w3t, const float* __restrict__ b1,
                   const float* __restrict__ b3, u16* __restrict__ tc,
                   u16* __restrict__ tf) {
  __shared__ u16 Al[128 * 32];
  __shared__ u16 Bl[128 * 32];
  const int tid = threadIdx.x, lane = tid & 63, wave = tid >> 6;
  const int f = blockIdx.x;
  const int xcd = f & 7, l = f >> 3;          // l in [0,256)
  const int mz = xcd * 64 + (l >> 2);         // (m,z) pair, 512 total
  const int z = mz >> 8;
  const int m0 = (mz & 255) * 128, n0 = (l & 3) * 128;
  const u16* A = hb + (size_t)m0 * 896 + z * 448;
  const u16* BT = (z ? w3t : w1t) + (size_t)n0 * 448;
  const float* bias = z ? b3 : b1;
  u16* T = z ? tf : tc;
  const int wm = wave & 1, wn = wave >> 1, q = lane >> 4, l16 = lane & 15;
  f32x4 acc[4][4];
  zero_acc(acc);
  gemm_tile_k(A, 896, BT, 448, 448, Al, Bl, wave, lane, acc);
  #pragma unroll
  for (int nt = 0; nt < 4; ++nt) {
    const int j = n0 + wn * 64 + nt * 16 + l16;
    if (j < 448) {
      const float bv = bias[j];
      #pragma unroll
      for (int mt = 0; mt < 4; ++mt)
        #pragma unroll
        for (int i = 0; i < 4; ++i) {
          const size_t row = (size_t)(m0 + wm * 64 + mt * 16 + q * 4 + i);
          T[row * 448 + j] = f2b(fmaxf(acc[mt][nt][i] + bv, 0.f));
        }
    }
  }
}

// ---------------- stage 2: out_z = T_z @ W_O{2,4} + b, f32 out ----------------
// grid 1024 = 8 xcd * 64 mz_local * 2 j (swizzled)
__global__ __launch_bounds__(256, 2)
void stage2_kernel(const u16* __restrict__ tc, const u16* __restrict__ tf,
                   const u16* __restrict__ w2t, const u16* __restrict__ w4t,
                   const float* __restrict__ b2_, const float* __restrict__ b4,
                   float* __restrict__ out) {
  __shared__ u16 Al[128 * 32];
  __shared__ u16 Bl[128 * 32];
  const int tid = threadIdx.x, lane = tid & 63, wave = tid >> 6;
  const int f = blockIdx.x;
  const int xcd = f & 7, l = f >> 3;          // l in [0,128)
  const int mz = xcd * 64 + (l >> 1);
  const int z = mz >> 8;
  const int m0 = (mz & 255) * 128, n0 = (l & 1) * 128;
  const u16* A = (z ? tf : tc) + (size_t)m0 * 448;
  const u16* BT = (z ? w4t : w2t) + (size_t)n0 * 448;
  const float* bias = z ? b4 : b2_;
  float* O = out + (size_t)z * 32768 * 256;
  const int wm = wave & 1, wn = wave >> 1, q = lane >> 4, l16 = lane & 15;
  f32x4 acc[4][4];
  zero_acc(acc);
  gemm_tile_k(A, 448, BT, 448, 448, Al, Bl, wave, lane, acc);
  #pragma unroll
  for (int nt = 0; nt < 4; ++nt) {
    const int j = n0 + wn * 64 + nt * 16 + l16;  // always < 256
    const float bv = bias[j];
    #pragma unroll
    for (int mt = 0; mt < 4; ++mt)
      #pragma unroll
      for (int i = 0; i < 4; ++i) {
        const size_t row = (size_t)(m0 + wm * 64 + mt * 16 + q * 4 + i);
        O[row * 256 + j] = acc[mt][nt][i] + bv;
      }
  }
}

// ---------------- host launch ----------------
extern "C" void kernel_launch(void* const* d_in, const int* in_sizes, int n_in,
                              void* d_out, int out_size, void* d_ws, size_t ws_size,
                              hipStream_t stream) {
  const float* y2   = (const float*)d_in[0];   // prev_y (B,2)
  const float* ph   = (const float*)d_in[1];   // prev_hidden (B,896)
  const float* cc   = (const float*)d_in[2];   // current_coarse (B,1)
  const float* W_R  = (const float*)d_in[3];   // (896, 2688)
  const float* W_Ic = (const float*)d_in[4];   // (2, 1344)
  const float* W_If = (const float*)d_in[5];   // (3, 1344)
  const float* W_O1 = (const float*)d_in[6];   // (448,448)
  const float* b_O1 = (const float*)d_in[7];
  const float* W_O2 = (const float*)d_in[8];   // (448,256)
  const float* b_O2 = (const float*)d_in[9];
  const float* W_O3 = (const float*)d_in[10];
  const float* b_O3 = (const float*)d_in[11];
  const float* W_O4 = (const float*)d_in[12];
  const float* b_O4 = (const float*)d_in[13];
  const float* bu   = (const float*)d_in[14];
  const float* br   = (const float*)d_in[15];
  const float* be   = (const float*)d_in[16];
  float* out = (float*)d_out;
  u16* ws  = (u16*)d_ws;

  // workspace layout (u16 elements), all offsets multiples of 8 (16B aligned)
  u16* WRT = ws;                               // 2688*896      = 2,408,448
  u16* W1T = WRT + (size_t)2688 * 896;         // 448*448
  u16* W2T = W1T + 448 * 448;                  // 256*448
  u16* W3T = W2T + 256 * 448;                  // 448*448
  u16* W4T = W3T + 448 * 448;                  // 256*448
  u16* phb = W4T + 256 * 448;                  // 32768*896 bf16
  u16* hb  = phb + (size_t)32768 * 896;        // 32768*896 bf16
  // Tc/Tf alias phb (dead after gate_kernel): 2 x 32768*448
  u16* Tc  = phb;
  u16* Tf  = phb + (size_t)32768 * 448;
  float* hidf = out + (size_t)2 * 32768 * 256; // hidden (output 2) in d_out

  dim3 tb(32, 8);
  cvt_f32_bf16<<<28672, 256, 0, stream>>>(ph, phb);
  transpose_f32_bf16<<<dim3(2688 / 32, 896 / 32), tb, 0, stream>>>(W_R, WRT, 896, 2688);
  transpose_f32_bf16<<<dim3(448 / 32, 448 / 32), tb, 0, stream>>>(W_O1, W1T, 448, 448);
  transpose_f32_bf16<<<dim3(256 / 32, 448 / 32), tb, 0, stream>>>(W_O2, W2T, 448, 256);
  transpose_f32_bf16<<<dim3(448 / 32, 448 / 32), tb, 0, stream>>>(W_O3, W3T, 448, 448);
  transpose_f32_bf16<<<dim3(256 / 32, 448 / 32), tb, 0, stream>>>(W_O4, W4T, 448, 256);

  gate_kernel<<<1792, 256, 0, stream>>>(phb, WRT, ph, y2, cc, W_Ic, W_If,
                                        bu, br, be, hidf, hb);
  stage1_kernel<<<2048, 256, 0, stream>>>(hb, W1T, W3T, b_O1, b_O3, Tc, Tf);
  stage2_kernel<<<1024, 256, 0, stream>>>(Tc, Tf, W2T, W4T, b_O2, b_O4, out);
}

// Round 2
// 703.362 us; speedup vs baseline: 1.5662x; 1.0064x over previous
//
#include <hip/hip_runtime.h>

// WaveRNN cell, MI355X. B=32768 H=896 S=448 Q=256.
// R3 changes vs R2:
//  - Issue-early double-buffered LDS staging in all GEMM K-loops: stage tile
//    t+1 BEFORE computing tile t, single __syncthreads per step. The vmcnt(0)
//    drain at the barrier now waits on loads that were covered by ~700cy of
//    ds_read+MFMA (R2 exposed full L2/L3 latency every K-step: ~5300cy/step
//    for ~430cy of work).
//  - stage1/stage2 LDS = 32KB (dbuf) -> 4-5 blocks/CU.
//  - merged the 4 W_O transposes into one launch (blockIdx.z).

typedef unsigned short u16;
typedef unsigned int u32;
typedef __attribute__((ext_vector_type(8))) short bf16x8;
typedef __attribute__((ext_vector_type(4))) float f32x4;

#define GAS __attribute__((address_space(1)))
#define LAS __attribute__((address_space(3)))

__device__ __forceinline__ u16 f2b(float f) {
  union { float f; u32 i; } v; v.f = f;
  return (u16)((v.i + 0x7fffu + ((v.i >> 16) & 1u)) >> 16);
}

__device__ __forceinline__ void gl_lds(const u16* g, u16* l) {
  __builtin_amdgcn_global_load_lds((const GAS void*)g, (LAS void*)l, 16, 0, 0);
}

// ---------------- f32 -> bf16 convert (prev_hidden) ----------------
__global__ void cvt_f32_bf16(const float* __restrict__ in, u16* __restrict__ outp) {
  const size_t i = ((size_t)blockIdx.x * 256 + threadIdx.x) * 4;
  const float4 v = *(const float4*)&in[i];
  ushort4 o;
  o.x = f2b(v.x); o.y = f2b(v.y); o.z = f2b(v.z); o.w = f2b(v.w);
  *(ushort4*)&outp[i] = o;
}

// --------- weight transpose, f32 row-major R x C -> bf16 C x R ---------
__device__ __forceinline__ void transpose_body(const float* __restrict__ in,
                                               u16* __restrict__ outp,
                                               int R, int C, int c0, int r0) {
  __shared__ u16 t[32][33];
  const int x = threadIdx.x, y = threadIdx.y;
  #pragma unroll
  for (int i = 0; i < 32; i += 8)
    t[y + i][x] = f2b(in[(size_t)(r0 + y + i) * C + (c0 + x)]);
  __syncthreads();
  #pragma unroll
  for (int i = 0; i < 32; i += 8)
    outp[(size_t)(c0 + y + i) * R + (r0 + x)] = t[x][y + i];
}

__global__ void transpose_f32_bf16(const float* __restrict__ in, u16* __restrict__ outp,
                                   int R, int C) {
  transpose_body(in, outp, R, C, blockIdx.x * 32, blockIdx.y * 32);
}

// merged W_O{1..4} transpose: z selects matrix; all R=448; C in {448,256}
__global__ void transpose_wo(const float* __restrict__ w1, const float* __restrict__ w2,
                             const float* __restrict__ w3, const float* __restrict__ w4,
                             u16* __restrict__ o1, u16* __restrict__ o2,
                             u16* __restrict__ o3, u16* __restrict__ o4) {
  const int z = blockIdx.z;
  const float* in = (z == 0) ? w1 : (z == 1) ? w2 : (z == 2) ? w3 : w4;
  u16* outp = (z == 0) ? o1 : (z == 1) ? o2 : (z == 2) ? o3 : o4;
  const int C = (z & 1) ? 256 : 448;
  const int c0 = blockIdx.x * 32;
  if (c0 >= C) return;
  transpose_body(in, outp, 448, C, c0, blockIdx.y * 32);
}

// ------------- 128x128 tile K-loop, double-buffered issue-early staging -----
// 4 waves as 2x2 grid of 64x64; BK=32; acc[4][4] f32x4. (stage1/stage2)
__device__ __forceinline__ void gemm_tile_k_db(const u16* __restrict__ A, int lda,
                                               const u16* __restrict__ BT, int ldb,
                                               int K, u16 (&Al)[2][128 * 32],
                                               u16 (&Bl)[2][128 * 32],
                                               int wave, int lane, f32x4 (&acc)[4][4]) {
  const int wm = wave & 1, wn = wave >> 1;
  const int q = lane >> 4, l16 = lane & 15;
  const int sr = lane >> 2;          // staging sub-row 0..15
  const int sc = (lane & 3) * 8;     // staging col offset (elements)
  const int nsteps = K / 32;
  #pragma unroll
  for (int i = 0; i < 2; ++i) {
    const int rr = wave * 32 + i * 16;
    gl_lds(A + (size_t)(rr + sr) * lda + sc, &Al[0][rr * 32]);
    gl_lds(BT + (size_t)(rr + sr) * ldb + sc, &Bl[0][rr * 32]);
  }
  __syncthreads();
  for (int t = 0; t < nsteps; ++t) {
    const int cur = t & 1;
    if (t + 1 < nsteps) {
      const int k0 = (t + 1) * 32;
      #pragma unroll
      for (int i = 0; i < 2; ++i) {
        const int rr = wave * 32 + i * 16;
        gl_lds(A + (size_t)(rr + sr) * lda + (k0 + sc), &Al[cur ^ 1][rr * 32]);
        gl_lds(BT + (size_t)(rr + sr) * ldb + (k0 + sc), &Bl[cur ^ 1][rr * 32]);
      }
    }
    bf16x8 af[4], bfr[4];
    #pragma unroll
    for (int t4 = 0; t4 < 4; ++t4) {
      af[t4]  = *(const bf16x8*)&Al[cur][(wm * 64 + t4 * 16 + l16) * 32 + q * 8];
      bfr[t4] = *(const bf16x8*)&Bl[cur][(wn * 64 + t4 * 16 + l16) * 32 + q * 8];
    }
    #pragma unroll
    for (int mt = 0; mt < 4; ++mt)
      #pragma unroll
      for (int nt = 0; nt < 4; ++nt)
        acc[mt][nt] = __builtin_amdgcn_mfma_f32_16x16x32_bf16(af[mt], bfr[nt],
                                                              acc[mt][nt], 0, 0, 0);
    __syncthreads();
  }
}

__device__ __forceinline__ void zero_acc(f32x4 (&acc)[4][4]) {
  const f32x4 z = {0.f, 0.f, 0.f, 0.f};
  #pragma unroll
  for (int mt = 0; mt < 4; ++mt)
    #pragma unroll
    for (int nt = 0; nt < 4; ++nt)
      acc[mt][nt] = z;
}

// ---------------- fused gate kernel (single K-loop, 3 acc sets, dbuf) --------
// grid 1792 = 8 xcd * 32 m_local * 7 j. Swizzle: xcd = f&7 so the 7 j-siblings
// of each m0 run back-to-back on one XCD (A-tile L2 reuse).
__global__ __launch_bounds__(256, 2)
void gate_kernel(const u16* __restrict__ phb, const u16* __restrict__ wrt,
                 const float* __restrict__ phf,
                 const float* __restrict__ y2, const float* __restrict__ cc,
                 const float* __restrict__ wic, const float* __restrict__ wif,
                 const float* __restrict__ bu, const float* __restrict__ br,
                 const float* __restrict__ be,
                 float* __restrict__ houtf, u16* __restrict__ hb) {
  __shared__ u16 Al[2][128 * 32];
  __shared__ u16 Bl[2][3][128 * 32];
  __shared__ float rowy[3 * 128];
  const int tid = threadIdx.x;
  const int lane = tid & 63, wave = tid >> 6;
  const int f = blockIdx.x;
  const int xcd = f & 7, l = f >> 3;          // 224 blocks per XCD
  const int m0 = (xcd * 32 + l / 7) * 128;
  const int j0 = (l % 7) * 128;
  if (tid < 128) {
    const int r = m0 + tid;
    rowy[tid]       = y2[2 * r];
    rowy[128 + tid] = y2[2 * r + 1];
    rowy[256 + tid] = cc[r];
  }
  const int wm = wave & 1, wn = wave >> 1;
  const int q = lane >> 4, l16 = lane & 15;
  const int sr = lane >> 2, sc = (lane & 3) * 8;

  f32x4 acc[3][4][4];
  {
    const f32x4 z = {0.f, 0.f, 0.f, 0.f};
    #pragma unroll
    for (int s = 0; s < 3; ++s)
      #pragma unroll
      for (int mt = 0; mt < 4; ++mt)
        #pragma unroll
        for (int nt = 0; nt < 4; ++nt)
          acc[s][mt][nt] = z;
  }

  const u16* Ab  = phb + (size_t)m0 * 896;
  const u16* Bb0 = wrt + (size_t)(0 * 896 + j0) * 896;
  const u16* Bb1 = wrt + (size_t)(1 * 896 + j0) * 896;
  const u16* Bb2 = wrt + (size_t)(2 * 896 + j0) * 896;

  // prologue stage into buffer 0
  #pragma unroll
  for (int i = 0; i < 2; ++i) {
    const int rr = wave * 32 + i * 16;
    const size_t go = (size_t)(rr + sr) * 896 + sc;
    gl_lds(Ab  + go, &Al[0][rr * 32]);
    gl_lds(Bb0 + go, &Bl[0][0][rr * 32]);
    gl_lds(Bb1 + go, &Bl[0][1][rr * 32]);
    gl_lds(Bb2 + go, &Bl[0][2][rr * 32]);
  }
  __syncthreads();

  for (int t = 0; t < 28; ++t) {
    const int cur = t & 1;
    if (t < 27) {
      const int k0 = (t + 1) * 32;
      #pragma unroll
      for (int i = 0; i < 2; ++i) {
        const int rr = wave * 32 + i * 16;
        const size_t go = (size_t)(rr + sr) * 896 + (k0 + sc);
        gl_lds(Ab  + go, &Al[cur ^ 1][rr * 32]);
        gl_lds(Bb0 + go, &Bl[cur ^ 1][0][rr * 32]);
        gl_lds(Bb1 + go, &Bl[cur ^ 1][1][rr * 32]);
        gl_lds(Bb2 + go, &Bl[cur ^ 1][2][rr * 32]);
      }
    }
    bf16x8 af[4];
    #pragma unroll
    for (int t4 = 0; t4 < 4; ++t4)
      af[t4] = *(const bf16x8*)&Al[cur][(wm * 64 + t4 * 16 + l16) * 32 + q * 8];
    #pragma unroll
    for (int s = 0; s < 3; ++s) {
      bf16x8 bfr[4];
      #pragma unroll
      for (int t4 = 0; t4 < 4; ++t4)
        bfr[t4] = *(const bf16x8*)&Bl[cur][s][(wn * 64 + t4 * 16 + l16) * 32 + q * 8];
      #pragma unroll
      for (int mt = 0; mt < 4; ++mt)
        #pragma unroll
        for (int nt = 0; nt < 4; ++nt)
          acc[s][mt][nt] = __builtin_amdgcn_mfma_f32_16x16x32_bf16(af[mt], bfr[nt],
                                                                   acc[s][mt][nt], 0, 0, 0);
    }
    __syncthreads();
  }

  // ---- fused epilogue: u, r, e, h in one place
  const int jb = j0 + wn * 64;
  const int rb = wm * 64 + q * 4;
  #pragma unroll
  for (int nt = 0; nt < 4; ++nt) {
    const int j = jb + nt * 16 + l16;
    float wu0, wu1, wu2, wr0, wr1, wr2, we0, we1, we2;
    if (j < 448) {
      wu0 = wic[j];       wu1 = wic[1344 + j];       wu2 = 0.f;
      wr0 = wic[448 + j]; wr1 = wic[1792 + j];       wr2 = 0.f;
      we0 = wic[896 + j]; we1 = wic[2240 + j];       we2 = 0.f;
    } else {
      const int jf = j - 448;
      wu0 = wif[jf];       wu1 = wif[1344 + jf]; wu2 = wif[2688 + jf];
      wr0 = wif[448 + jf]; wr1 = wif[1792 + jf]; wr2 = wif[3136 + jf];
      we0 = wif[896 + jf]; we1 = wif[2240 + jf]; we2 = wif[3584 + jf];
    }
    const float bju = bu[j], bjr = br[j], bje = be[j];
    #pragma unroll
    for (int mt = 0; mt < 4; ++mt) {
      const int rl = rb + mt * 16;
      #pragma unroll
      for (int i = 0; i < 4; ++i) {
        const float y0 = rowy[rl + i], y1 = rowy[128 + rl + i], yc = rowy[256 + rl + i];
        const float gu = acc[0][mt][nt][i] + y0 * wu0 + y1 * wu1 + yc * wu2 + bju;
        const float gr = acc[1][mt][nt][i] + y0 * wr0 + y1 * wr1 + yc * wr2 + bjr;
        const float uu = 1.f / (1.f + __expf(-gu));
        const float rg = 1.f / (1.f + __expf(-gr));
        const float ev = tanhf(rg * acc[2][mt][nt][i] +
                               y0 * we0 + y1 * we1 + yc * we2 + bje);
        const size_t grow = (size_t)(m0 + rl + i);
        const float phv = phf[grow * 896 + j];
        const float h = uu * phv + (1.f - uu) * ev;
        houtf[grow * 896 + j] = h;
        hb[grow * 896 + j] = f2b(h);
      }
    }
  }
}

// ---------------- stage 1: T_z = relu(h_z @ W_O{1,3} + b), bf16 out ----------
// grid 2048 = 8 xcd * 64 mz_local * 4 j (swizzled; last j tile: rows >=448 of
// BT read garbage in-ws bytes; write masked by j<448).
__global__ __launch_bounds__(256, 2)
void stage1_kernel(const u16* __restrict__ hb, const u16* __restrict__ w1t,
                   const u16* __restrict__ w3t, const float* __restrict__ b1,
                   const float* __restrict__ b3, u16* __restrict__ tc,
                   u16* __restrict__ tf) {
  __shared__ u16 Al[2][128 * 32];
  __shared__ u16 Bl[2][128 * 32];
  const int tid = threadIdx.x, lane = tid & 63, wave = tid >> 6;
  const int f = blockIdx.x;
  const int xcd = f & 7, l = f >> 3;          // l in [0,256)
  const int mz = xcd * 64 + (l >> 2);         // (m,z) pair, 512 total
  const int z = mz >> 8;
  const int m0 = (mz & 255) * 128, n0 = (l & 3) * 128;
  const u16* A = hb + (size_t)m0 * 896 + z * 448;
  const u16* BT = (z ? w3t : w1t) + (size_t)n0 * 448;
  const float* bias = z ? b3 : b1;
  u16* T = z ? tf : tc;
  const int wm = wave & 1, wn = wave >> 1, q = lane >> 4, l16 = lane & 15;
  f32x4 acc[4][4];
  zero_acc(acc);
  gemm_tile_k_db(A, 896, BT, 448, 448, Al, Bl, wave, lane, acc);
  #pragma unroll
  for (int nt = 0; nt < 4; ++nt) {
    const int j = n0 + wn * 64 + nt * 16 + l16;
    if (j < 448) {
      const float bv = bias[j];
      #pragma unroll
      for (int mt = 0; mt < 4; ++mt)
        #pragma unroll
        for (int i = 0; i < 4; ++i) {
          const size_t row = (size_t)(m0 + wm * 64 + mt * 16 + q * 4 + i);
          T[row * 448 + j] = f2b(fmaxf(acc[mt][nt][i] + bv, 0.f));
        }
    }
  }
}

// ---------------- stage 2: out_z = T_z @ W_O{2,4} + b, f32 out ----------------
// grid 1024 = 8 xcd * 64 mz_local * 2 j (swizzled)
__global__ __launch_bounds__(256, 2)
void stage2_kernel(const u16* __restrict__ tc, const u16* __restrict__ tf,
                   const u16* __restrict__ w2t, const u16* __restrict__ w4t,
                   const float* __restrict__ b2_, const float* __restrict__ b4,
                   float* __restrict__ out) {
  __shared__ u16 Al[2][128 * 32];
  __shared__ u16 Bl[2][128 * 32];
  const int tid = threadIdx.x, lane = tid & 63, wave = tid >> 6;
  const int f = blockIdx.x;
  const int xcd = f & 7, l = f >> 3;          // l in [0,128)
  const int mz = xcd * 64 + (l >> 1);
  const int z = mz >> 8;
  const int m0 = (mz & 255) * 128, n0 = (l & 1) * 128;
  const u16* A = (z ? tf : tc) + (size_t)m0 * 448;
  const u16* BT = (z ? w4t : w2t) + (size_t)n0 * 448;
  const float* bias = z ? b4 : b2_;
  float* O = out + (size_t)z * 32768 * 256;
  const int wm = wave & 1, wn = wave >> 1, q = lane >> 4, l16 = lane & 15;
  f32x4 acc[4][4];
  zero_acc(acc);
  gemm_tile_k_db(A, 448, BT, 448, 448, Al, Bl, wave, lane, acc);
  #pragma unroll
  for (int nt = 0; nt < 4; ++nt) {
    const int j = n0 + wn * 64 + nt * 16 + l16;  // always < 256
    const float bv = bias[j];
    #pragma unroll
    for (int mt = 0; mt < 4; ++mt)
      #pragma unroll
      for (int i = 0; i < 4; ++i) {
        const size_t row = (size_t)(m0 + wm * 64 + mt * 16 + q * 4 + i);
        O[row * 256 + j] = acc[mt][nt][i] + bv;
      }
  }
}

// ---------------- host launch ----------------
extern "C" void kernel_launch(void* const* d_in, const int* in_sizes, int n_in,
                              void* d_out, int out_size, void* d_ws, size_t ws_size,
                              hipStream_t stream) {
  const float* y2   = (const float*)d_in[0];   // prev_y (B,2)
  const float* ph   = (const float*)d_in[1];   // prev_hidden (B,896)
  const float* cc   = (const float*)d_in[2];   // current_coarse (B,1)
  const float* W_R  = (const float*)d_in[3];   // (896, 2688)
  const float* W_Ic = (const float*)d_in[4];   // (2, 1344)
  const float* W_If = (const float*)d_in[5];   // (3, 1344)
  const float* W_O1 = (const float*)d_in[6];   // (448,448)
  const float* b_O1 = (const float*)d_in[7];
  const float* W_O2 = (const float*)d_in[8];   // (448,256)
  const float* b_O2 = (const float*)d_in[9];
  const float* W_O3 = (const float*)d_in[10];
  const float* b_O3 = (const float*)d_in[11];
  const float* W_O4 = (const float*)d_in[12];
  const float* b_O4 = (const float*)d_in[13];
  const float* bu   = (const float*)d_in[14];
  const float* br   = (const float*)d_in[15];
  const float* be   = (const float*)d_in[16];
  float* out = (float*)d_out;
  u16* ws  = (u16*)d_ws;

  // workspace layout (u16 elements), all offsets multiples of 8 (16B aligned)
  u16* WRT = ws;                               // 2688*896      = 2,408,448
  u16* W1T = WRT + (size_t)2688 * 896;         // 448*448
  u16* W2T = W1T + 448 * 448;                  // 256*448
  u16* W3T = W2T + 256 * 448;                  // 448*448
  u16* W4T = W3T + 448 * 448;                  // 256*448
  u16* phb = W4T + 256 * 448;                  // 32768*896 bf16
  u16* hb  = phb + (size_t)32768 * 896;        // 32768*896 bf16
  // Tc/Tf alias phb (dead after gate_kernel): 2 x 32768*448
  u16* Tc  = phb;
  u16* Tf  = phb + (size_t)32768 * 448;
  float* hidf = out + (size_t)2 * 32768 * 256; // hidden (output 2) in d_out

  dim3 tb(32, 8);
  cvt_f32_bf16<<<28672, 256, 0, stream>>>(ph, phb);
  transpose_f32_bf16<<<dim3(2688 / 32, 896 / 32), tb, 0, stream>>>(W_R, WRT, 896, 2688);
  transpose_wo<<<dim3(14, 14, 4), tb, 0, stream>>>(W_O1, W_O2, W_O3, W_O4,
                                                   W1T, W2T, W3T, W4T);

  gate_kernel<<<1792, 256, 0, stream>>>(phb, WRT, ph, y2, cc, W_Ic, W_If,
                                        bu, br, be, hidf, hb);
  stage1_kernel<<<2048, 256, 0, stream>>>(hb, W1T, W3T, b_O1, b_O3, Tc, Tf);
  stage2_kernel<<<1024, 256, 0, stream>>>(Tc, Tf, W2T, W4T, b_O2, b_O4, out);
}

// Round 3
// 628.874 us; speedup vs baseline: 1.7517x; 1.1184x over previous
//
#include <hip/hip_runtime.h>

// WaveRNN cell, MI355X. B=32768 H=896 S=448 Q=256.
// R3 changes vs R2:
//  - gate_kernel rebuilt: R2 was register-capped at ~6 waves/CU (unified
//    VGPR+AGPR: 128+192=320/wave). New: 1024-thr blocks, 16 waves as 4x4,
//    wave owns 32 rows x 96 gate-interleaved cols -> acc[2][3][2] = 48 regs,
//    ~115 total -> 16 waves/CU (50% occ). Gate cols interleaved (nn=jj*3+s)
//    so each thread holds its own (u,r,e) triple for the epilogue.
//  - Staging: 32 gl_lds/iter = exactly 2/wave -> NBUF=3 ring, counted
//    s_waitcnt vmcnt(2) + ONE raw s_barrier per iter. No vmcnt(0) drain;
//    loads stay in flight 2 iters deep (T3/T4-lite).
//  - j-major XCD swizzle: per generation each XCD's B slice (688KB) is
//    L2-resident; A re-reads come from L3, prefetched 2 iters ahead.
//  - stage1/stage2 reverted to R1 single-buffer (dbuf cost them occupancy).

typedef unsigned short u16;
typedef unsigned int u32;
typedef __attribute__((ext_vector_type(8))) short bf16x8;
typedef __attribute__((ext_vector_type(4))) float f32x4;

#define GAS __attribute__((address_space(1)))
#define LAS __attribute__((address_space(3)))

__device__ __forceinline__ u16 f2b(float f) {
  union { float f; u32 i; } v; v.f = f;
  return (u16)((v.i + 0x7fffu + ((v.i >> 16) & 1u)) >> 16);
}

__device__ __forceinline__ void gl_lds(const u16* g, u16* l) {
  __builtin_amdgcn_global_load_lds((const GAS void*)g, (LAS void*)l, 16, 0, 0);
}

// ---------------- f32 -> bf16 convert (prev_hidden) ----------------
__global__ void cvt_f32_bf16(const float* __restrict__ in, u16* __restrict__ outp) {
  const size_t i = ((size_t)blockIdx.x * 256 + threadIdx.x) * 4;
  const float4 v = *(const float4*)&in[i];
  ushort4 o;
  o.x = f2b(v.x); o.y = f2b(v.y); o.z = f2b(v.z); o.w = f2b(v.w);
  *(ushort4*)&outp[i] = o;
}

// --------- weight transpose, f32 row-major R x C -> bf16 C x R ---------
__device__ __forceinline__ void transpose_body(const float* __restrict__ in,
                                               u16* __restrict__ outp,
                                               int R, int C, int c0, int r0) {
  __shared__ u16 t[32][33];
  const int x = threadIdx.x, y = threadIdx.y;
  #pragma unroll
  for (int i = 0; i < 32; i += 8)
    t[y + i][x] = f2b(in[(size_t)(r0 + y + i) * C + (c0 + x)]);
  __syncthreads();
  #pragma unroll
  for (int i = 0; i < 32; i += 8)
    outp[(size_t)(c0 + y + i) * R + (r0 + x)] = t[x][y + i];
}

__global__ void transpose_f32_bf16(const float* __restrict__ in, u16* __restrict__ outp,
                                   int R, int C) {
  transpose_body(in, outp, R, C, blockIdx.x * 32, blockIdx.y * 32);
}

// merged W_O{1..4} transpose: z selects matrix; all R=448; C in {448,256}
__global__ void transpose_wo(const float* __restrict__ w1, const float* __restrict__ w2,
                             const float* __restrict__ w3, const float* __restrict__ w4,
                             u16* __restrict__ o1, u16* __restrict__ o2,
                             u16* __restrict__ o3, u16* __restrict__ o4) {
  const int z = blockIdx.z;
  const float* in = (z == 0) ? w1 : (z == 1) ? w2 : (z == 2) ? w3 : w4;
  u16* outp = (z == 0) ? o1 : (z == 1) ? o2 : (z == 2) ? o3 : o4;
  const int C = (z & 1) ? 256 : 448;
  const int c0 = blockIdx.x * 32;
  if (c0 >= C) return;
  transpose_body(in, outp, 448, C, c0, blockIdx.y * 32);
}

// ------------- 128x128 tile K-loop (single-buffer, R1 version) --------------
// 4 waves as 2x2 grid of 64x64; BK=32; acc[4][4] f32x4. (stage1/stage2)
__device__ __forceinline__ void gemm_tile_k(const u16* __restrict__ A, int lda,
                                            const u16* __restrict__ BT, int ldb,
                                            int K, u16* Al, u16* Bl,
                                            int wave, int lane, f32x4 (&acc)[4][4]) {
  const int wm = wave & 1, wn = wave >> 1;
  const int q = lane >> 4, l16 = lane & 15;
  const int sr = lane >> 2;          // staging sub-row 0..15
  const int sc = (lane & 3) * 8;     // staging col offset (elements)
  for (int k0 = 0; k0 < K; k0 += 32) {
    #pragma unroll
    for (int i = 0; i < 2; ++i) {
      const int rr = wave * 32 + i * 16;  // wave-uniform row base
      gl_lds(A + (size_t)(rr + sr) * lda + (k0 + sc), &Al[rr * 32]);
      gl_lds(BT + (size_t)(rr + sr) * ldb + (k0 + sc), &Bl[rr * 32]);
    }
    __syncthreads();
    bf16x8 af[4], bfr[4];
    #pragma unroll
    for (int t = 0; t < 4; ++t) {
      af[t]  = *(const bf16x8*)&Al[(wm * 64 + t * 16 + l16) * 32 + q * 8];
      bfr[t] = *(const bf16x8*)&Bl[(wn * 64 + t * 16 + l16) * 32 + q * 8];
    }
    #pragma unroll
    for (int mt = 0; mt < 4; ++mt)
      #pragma unroll
      for (int nt = 0; nt < 4; ++nt)
        acc[mt][nt] = __builtin_amdgcn_mfma_f32_16x16x32_bf16(af[mt], bfr[nt],
                                                              acc[mt][nt], 0, 0, 0);
    __syncthreads();
  }
}

__device__ __forceinline__ void zero_acc(f32x4 (&acc)[4][4]) {
  const f32x4 z = {0.f, 0.f, 0.f, 0.f};
  #pragma unroll
  for (int mt = 0; mt < 4; ++mt)
    #pragma unroll
    for (int nt = 0; nt < 4; ++nt)
      acc[mt][nt] = z;
}

// ---------------- fused gate kernel: 1024 thr, 16 waves, 3-buf ring ---------
// Block tile: 128 rows x (3 gates x 128 cols), gate-interleaved column tiles:
// nn = jj*3 + s (jj in 0..7: 16-col group; s: gate). Wave (wm=wave&3,
// wn=wave>>2): rows wm*32+mt*16, col tiles nn=(2*wn+jj2)*3+s.
// LDS per buf: A 128x32 at [0..4096), B 24 tiles of 16x32 at [4096+nn*512).
// Staging: 32 gl_lds/iter, unit u = 2*wave+{0,1}; u<8 -> A rows u*16,
// u>=8 -> B tile u-8. Ring of 3 bufs, prefetch t+2, s_waitcnt vmcnt(2),
// one s_barrier per iter (buf (t+2)%3 was last read at t-1, before barrier t).
__global__ __launch_bounds__(1024, 4)
void gate_kernel(const u16* __restrict__ phb, const u16* __restrict__ wrt,
                 const float* __restrict__ phf,
                 const float* __restrict__ y2, const float* __restrict__ cc,
                 const float* __restrict__ wic, const float* __restrict__ wif,
                 const float* __restrict__ bu, const float* __restrict__ br,
                 const float* __restrict__ be,
                 float* __restrict__ houtf, u16* __restrict__ hb) {
  __shared__ u16 Sl[3][16384];
  __shared__ float rowy[3 * 128];
  const int tid = threadIdx.x;
  const int lane = tid & 63, wave = tid >> 6;
  const int f = blockIdx.x;
  const int xcd = f & 7, l = f >> 3;            // 224 blocks per XCD
  const int m0 = (xcd * 32 + (l & 31)) * 128;   // j-major within XCD:
  const int j0 = (l >> 5) * 128;                // B slice L2-resident per gen
  if (tid < 128) {
    const int r = m0 + tid;
    rowy[tid]       = y2[2 * r];
    rowy[128 + tid] = y2[2 * r + 1];
    rowy[256 + tid] = cc[r];
    asm volatile("s_waitcnt lgkmcnt(0)" ::: "memory");
  }
  const int wm = wave & 3, wn = wave >> 2;
  const int q = lane >> 4, l16 = lane & 15;
  const int sr = lane >> 2, sc = (lane & 3) * 8;

  // per-wave staging units
  const int u0 = 2 * wave, u1 = u0 + 1;
  const u16* g0; const u16* g1; int lo0, lo1;
  if (u0 < 8) { g0 = phb + (size_t)(m0 + u0 * 16 + sr) * 896 + sc; lo0 = u0 * 512; }
  else { const int nn = u0 - 8, jj = nn / 3, s = nn % 3;
         g0 = wrt + (size_t)(s * 896 + j0 + jj * 16 + sr) * 896 + sc;
         lo0 = 4096 + nn * 512; }
  if (u1 < 8) { g1 = phb + (size_t)(m0 + u1 * 16 + sr) * 896 + sc; lo1 = u1 * 512; }
  else { const int nn = u1 - 8, jj = nn / 3, s = nn % 3;
         g1 = wrt + (size_t)(s * 896 + j0 + jj * 16 + sr) * 896 + sc;
         lo1 = 4096 + nn * 512; }

  f32x4 acc[2][3][2];   // [jj2][s][mt]
  {
    const f32x4 z = {0.f, 0.f, 0.f, 0.f};
    #pragma unroll
    for (int a = 0; a < 2; ++a)
      #pragma unroll
      for (int s = 0; s < 3; ++s)
        #pragma unroll
        for (int m = 0; m < 2; ++m)
          acc[a][s][m] = z;
  }

  auto stage = [&](int t_) {
    const int b_ = t_ % 3;
    const int k_ = t_ * 32;
    gl_lds(g0 + k_, &Sl[b_][lo0]);
    gl_lds(g1 + k_, &Sl[b_][lo1]);
  };

  stage(0);
  stage(1);
  for (int t = 0; t < 28; ++t) {
    if (t < 27) asm volatile("s_waitcnt vmcnt(2)" ::: "memory");
    else        asm volatile("s_waitcnt vmcnt(0)" ::: "memory");
    __builtin_amdgcn_s_barrier();
    __builtin_amdgcn_sched_barrier(0);
    const u16* Sb = Sl[t % 3];
    bf16x8 af[2];
    #pragma unroll
    for (int mt = 0; mt < 2; ++mt)
      af[mt] = *(const bf16x8*)&Sb[(wm * 32 + mt * 16 + l16) * 32 + q * 8];
    #pragma unroll
    for (int jj2 = 0; jj2 < 2; ++jj2)
      #pragma unroll
      for (int s = 0; s < 3; ++s) {
        const int nn = (2 * wn + jj2) * 3 + s;
        const bf16x8 bf_ = *(const bf16x8*)&Sb[4096 + nn * 512 + l16 * 32 + q * 8];
        #pragma unroll
        for (int mt = 0; mt < 2; ++mt)
          acc[jj2][s][mt] = __builtin_amdgcn_mfma_f32_16x16x32_bf16(
              af[mt], bf_, acc[jj2][s][mt], 0, 0, 0);
      }
    if (t + 2 < 28) stage(t + 2);
  }

  // ---- fused epilogue: u, r, e, h; each thread owns its (u,r,e) triple
  #pragma unroll
  for (int jj2 = 0; jj2 < 2; ++jj2) {
    const int j = j0 + (2 * wn + jj2) * 16 + l16;
    float wu0, wu1, wu2, wr0, wr1, wr2, we0, we1, we2;
    if (j < 448) {
      wu0 = wic[j];       wu1 = wic[1344 + j];       wu2 = 0.f;
      wr0 = wic[448 + j]; wr1 = wic[1792 + j];       wr2 = 0.f;
      we0 = wic[896 + j]; we1 = wic[2240 + j];       we2 = 0.f;
    } else {
      const int jf = j - 448;
      wu0 = wif[jf];       wu1 = wif[1344 + jf]; wu2 = wif[2688 + jf];
      wr0 = wif[448 + jf]; wr1 = wif[1792 + jf]; wr2 = wif[3136 + jf];
      we0 = wif[896 + jf]; we1 = wif[2240 + jf]; we2 = wif[3584 + jf];
    }
    const float bju = bu[j], bjr = br[j], bje = be[j];
    #pragma unroll
    for (int mt = 0; mt < 2; ++mt) {
      const int rl = wm * 32 + mt * 16 + q * 4;
      #pragma unroll
      for (int i = 0; i < 4; ++i) {
        const float y0 = rowy[rl + i], y1 = rowy[128 + rl + i], yc = rowy[256 + rl + i];
        const float gu = acc[jj2][0][mt][i] + y0 * wu0 + y1 * wu1 + yc * wu2 + bju;
        const float gr = acc[jj2][1][mt][i] + y0 * wr0 + y1 * wr1 + yc * wr2 + bjr;
        const float uu = 1.f / (1.f + __expf(-gu));
        const float rg = 1.f / (1.f + __expf(-gr));
        const float ev = tanhf(rg * acc[jj2][2][mt][i] +
                               y0 * we0 + y1 * we1 + yc * we2 + bje);
        const size_t grow = (size_t)(m0 + rl + i);
        const float phv = phf[grow * 896 + j];
        const float h = uu * phv + (1.f - uu) * ev;
        houtf[grow * 896 + j] = h;
        hb[grow * 896 + j] = f2b(h);
      }
    }
  }
}

// ---------------- stage 1: T_z = relu(h_z @ W_O{1,3} + b), bf16 out ----------
// grid 2048 = 8 xcd * 64 mz_local * 4 j (swizzled; last j tile: rows >=448 of
// BT read garbage in-ws bytes; write masked by j<448).
__global__ __launch_bounds__(256, 2)
void stage1_kernel(const u16* __restrict__ hb, const u16* __restrict__ w1t,
                   const u16* __restrict__ w3t, const float* __restrict__ b1,
                   const float* __restrict__ b3, u16* __restrict__ tc,
                   u16* __restrict__ tf) {
  __shared__ u16 Al[128 * 32];
  __shared__ u16 Bl[128 * 32];
  const int tid = threadIdx.x, lane = tid & 63, wave = tid >> 6;
  const int f = blockIdx.x;
  const int xcd = f & 7, l = f >> 3;          // l in [0,256)
  const int mz = xcd * 64 + (l >> 2);         // (m,z) pair, 512 total
  const int z = mz >> 8;
  const int m0 = (mz & 255) * 128, n0 = (l & 3) * 128;
  const u16* A = hb + (size_t)m0 * 896 + z * 448;
  const u16* BT = (z ? w3t : w1t) + (size_t)n0 * 448;
  const float* bias = z ? b3 : b1;
  u16* T = z ? tf : tc;
  const int wm = wave & 1, wn = wave >> 1, q = lane >> 4, l16 = lane & 15;
  f32x4 acc[4][4];
  zero_acc(acc);
  gemm_tile_k(A, 896, BT, 448, 448, Al, Bl, wave, lane, acc);
  #pragma unroll
  for (int nt = 0; nt < 4; ++nt) {
    const int j = n0 + wn * 64 + nt * 16 + l16;
    if (j < 448) {
      const float bv = bias[j];
      #pragma unroll
      for (int mt = 0; mt < 4; ++mt)
        #pragma unroll
        for (int i = 0; i < 4; ++i) {
          const size_t row = (size_t)(m0 + wm * 64 + mt * 16 + q * 4 + i);
          T[row * 448 + j] = f2b(fmaxf(acc[mt][nt][i] + bv, 0.f));
        }
    }
  }
}

// ---------------- stage 2: out_z = T_z @ W_O{2,4} + b, f32 out ----------------
// grid 1024 = 8 xcd * 64 mz_local * 2 j (swizzled)
__global__ __launch_bounds__(256, 2)
void stage2_kernel(const u16* __restrict__ tc, const u16* __restrict__ tf,
                   const u16* __restrict__ w2t, const u16* __restrict__ w4t,
                   const float* __restrict__ b2_, const float* __restrict__ b4,
                   float* __restrict__ out) {
  __shared__ u16 Al[128 * 32];
  __shared__ u16 Bl[128 * 32];
  const int tid = threadIdx.x, lane = tid & 63, wave = tid >> 6;
  const int f = blockIdx.x;
  const int xcd = f & 7, l = f >> 3;          // l in [0,128)
  const int mz = xcd * 64 + (l >> 1);
  const int z = mz >> 8;
  const int m0 = (mz & 255) * 128, n0 = (l & 1) * 128;
  const u16* A = (z ? tf : tc) + (size_t)m0 * 448;
  const u16* BT = (z ? w4t : w2t) + (size_t)n0 * 448;
  const float* bias = z ? b4 : b2_;
  float* O = out + (size_t)z * 32768 * 256;
  const int wm = wave & 1, wn = wave >> 1, q = lane >> 4, l16 = lane & 15;
  f32x4 acc[4][4];
  zero_acc(acc);
  gemm_tile_k(A, 448, BT, 448, 448, Al, Bl, wave, lane, acc);
  #pragma unroll
  for (int nt = 0; nt < 4; ++nt) {
    const int j = n0 + wn * 64 + nt * 16 + l16;  // always < 256
    const float bv = bias[j];
    #pragma unroll
    for (int mt = 0; mt < 4; ++mt)
      #pragma unroll
      for (int i = 0; i < 4; ++i) {
        const size_t row = (size_t)(m0 + wm * 64 + mt * 16 + q * 4 + i);
        O[row * 256 + j] = acc[mt][nt][i] + bv;
      }
  }
}

// ---------------- host launch ----------------
extern "C" void kernel_launch(void* const* d_in, const int* in_sizes, int n_in,
                              void* d_out, int out_size, void* d_ws, size_t ws_size,
                              hipStream_t stream) {
  const float* y2   = (const float*)d_in[0];   // prev_y (B,2)
  const float* ph   = (const float*)d_in[1];   // prev_hidden (B,896)
  const float* cc   = (const float*)d_in[2];   // current_coarse (B,1)
  const float* W_R  = (const float*)d_in[3];   // (896, 2688)
  const float* W_Ic = (const float*)d_in[4];   // (2, 1344)
  const float* W_If = (const float*)d_in[5];   // (3, 1344)
  const float* W_O1 = (const float*)d_in[6];   // (448,448)
  const float* b_O1 = (const float*)d_in[7];
  const float* W_O2 = (const float*)d_in[8];   // (448,256)
  const float* b_O2 = (const float*)d_in[9];
  const float* W_O3 = (const float*)d_in[10];
  const float* b_O3 = (const float*)d_in[11];
  const float* W_O4 = (const float*)d_in[12];
  const float* b_O4 = (const float*)d_in[13];
  const float* bu   = (const float*)d_in[14];
  const float* br   = (const float*)d_in[15];
  const float* be   = (const float*)d_in[16];
  float* out = (float*)d_out;
  u16* ws  = (u16*)d_ws;

  // workspace layout (u16 elements), all offsets multiples of 8 (16B aligned)
  u16* WRT = ws;                               // 2688*896      = 2,408,448
  u16* W1T = WRT + (size_t)2688 * 896;         // 448*448
  u16* W2T = W1T + 448 * 448;                  // 256*448
  u16* W3T = W2T + 256 * 448;                  // 448*448
  u16* W4T = W3T + 448 * 448;                  // 256*448
  u16* phb = W4T + 256 * 448;                  // 32768*896 bf16
  u16* hb  = phb + (size_t)32768 * 896;        // 32768*896 bf16
  // Tc/Tf alias phb (dead after gate_kernel): 2 x 32768*448
  u16* Tc  = phb;
  u16* Tf  = phb + (size_t)32768 * 448;
  float* hidf = out + (size_t)2 * 32768 * 256; // hidden (output 2) in d_out

  dim3 tb(32, 8);
  cvt_f32_bf16<<<28672, 256, 0, stream>>>(ph, phb);
  transpose_f32_bf16<<<dim3(2688 / 32, 896 / 32), tb, 0, stream>>>(W_R, WRT, 896, 2688);
  transpose_wo<<<dim3(14, 14, 4), tb, 0, stream>>>(W_O1, W_O2, W_O3, W_O4,
                                                   W1T, W2T, W3T, W4T);

  gate_kernel<<<1792, 1024, 0, stream>>>(phb, WRT, ph, y2, cc, W_Ic, W_If,
                                         bu, br, be, hidf, hb);
  stage1_kernel<<<2048, 256, 0, stream>>>(hb, W1T, W3T, b_O1, b_O3, Tc, Tf);
  stage2_kernel<<<1024, 256, 0, stream>>>(Tc, Tf, W2T, W4T, b_O2, b_O4, out);
}